// Round 8
// baseline (409.047 us; speedup 1.0000x reference)
//
#include <hip/hip_runtime.h>
#include <math.h>

#define NN 4096      // nodes
#define CC 512       // concat dim = 8 heads * 64
#define MB (1024*1024)
#define LOG2E 1.4426950408889634f

typedef __attribute__((ext_vector_type(8))) __bf16 bf16x8;
typedef __attribute__((ext_vector_type(4))) float f32x4;
typedef unsigned short ushort_t;
typedef unsigned int uint_t;
typedef unsigned char uchar_t;

#if __has_builtin(__builtin_amdgcn_exp2f)
#define EXP2(x) __builtin_amdgcn_exp2f(x)
#else
#define EXP2(x) exp2f(x)
#endif

static __device__ __forceinline__ float elu1(float x){ return x > 0.f ? x : (__expf(x)-1.f); }
static __device__ __forceinline__ ushort_t f2bf(float f){
    union { float f; uint_t u; } v; v.f = f;
    uint_t r = (v.u + 0x7FFFu + ((v.u >> 16) & 1u)) >> 16;
    return (ushort_t)r;
}
static __device__ __forceinline__ float bf2f(ushort_t h){
    union { uint_t u; float f; } q; q.u = ((uint_t)h) << 16; return q.f;
}

// ---- prep: W_att [8][512(k)][64(f)] -> Wh/Wl [512(c)][512(k)] bf16 hi/lo
//           Wout [512(k)][32(n)] -> WoutT_h/l [32(n)][512(k)] bf16 hi/lo
__global__ void k_prep(const float* __restrict__ Watt, const float* __restrict__ Wout,
                       ushort_t* __restrict__ Wh, ushort_t* __restrict__ Wl,
                       ushort_t* __restrict__ Wth, ushort_t* __restrict__ Wtl){
    int idx = blockIdx.x*256 + threadIdx.x;
    if (idx < 512*128){
        int c = idx >> 7, kq = idx & 127, k = kq*4;
        ushort4 h4, l4;
        float v[4];
        #pragma unroll
        for(int j=0;j<4;j++)
            v[j] = Watt[(c>>6)*(512*64) + (k+j)*64 + (c&63)];
        h4.x = f2bf(v[0]); h4.y = f2bf(v[1]); h4.z = f2bf(v[2]); h4.w = f2bf(v[3]);
        l4.x = f2bf(v[0]-bf2f(h4.x)); l4.y = f2bf(v[1]-bf2f(h4.y));
        l4.z = f2bf(v[2]-bf2f(h4.z)); l4.w = f2bf(v[3]-bf2f(h4.w));
        *(ushort4*)&Wh[(size_t)c*512 + k] = h4;
        *(ushort4*)&Wl[(size_t)c*512 + k] = l4;
    } else if (idx < 512*128 + 32*128){
        int idx2 = idx - 512*128;
        int n = idx2 >> 7, kq = idx2 & 127, k = kq*4;
        ushort4 h4, l4;
        float v[4];
        #pragma unroll
        for(int j=0;j<4;j++)
            v[j] = Wout[(size_t)(k+j)*32 + n];
        h4.x = f2bf(v[0]); h4.y = f2bf(v[1]); h4.z = f2bf(v[2]); h4.w = f2bf(v[3]);
        l4.x = f2bf(v[0]-bf2f(h4.x)); l4.y = f2bf(v[1]-bf2f(h4.y));
        l4.z = f2bf(v[2]-bf2f(h4.z)); l4.w = f2bf(v[3]-bf2f(h4.w));
        *(ushort4*)&Wth[(size_t)n*512 + k] = h4;
        *(ushort4*)&Wtl[(size_t)n*512 + k] = l4;
    }
}

// ---- split x [4096][512] f32 -> xh/xl bf16
__global__ void k_splitx(const float* __restrict__ x,
                         ushort_t* __restrict__ xh, ushort_t* __restrict__ xl){
    int idx = blockIdx.x*256 + threadIdx.x;     // < 4096*512/4
    float4 v = *(const float4*)&x[(size_t)idx*4];
    ushort4 h4, l4;
    h4.x = f2bf(v.x); h4.y = f2bf(v.y); h4.z = f2bf(v.z); h4.w = f2bf(v.w);
    l4.x = f2bf(v.x-bf2f(h4.x)); l4.y = f2bf(v.y-bf2f(h4.y));
    l4.z = f2bf(v.z-bf2f(h4.z)); l4.w = f2bf(v.w-bf2f(h4.w));
    *(ushort4*)&xh[(size_t)idx*4] = h4;
    *(ushort4*)&xl[(size_t)idx*4] = l4;
}

// ---- pack adjacency to bits
__global__ void k_pack(const int* __restrict__ adj, uint_t* __restrict__ abits){
    int idx = blockIdx.x*256 + threadIdx.x;            // < 4096*128
    int i = idx >> 7, q = idx & 127;
    const int4* p = (const int4*)&adj[(size_t)i*NN + q*32];
    uint_t m = 0;
    #pragma unroll
    for(int g=0; g<8; g++){
        int4 v = p[g];
        m |= (uint_t)(v.x > 0) << (g*4 + 0);
        m |= (uint_t)(v.y > 0) << (g*4 + 1);
        m |= (uint_t)(v.z > 0) << (g*4 + 2);
        m |= (uint_t)(v.w > 0) << (g*4 + 3);
    }
    abits[idx] = m;
}

// ---- gemm1 via MFMA (bf16 hi/lo split): h = x @ W_all, FUSED scores1.
// grid (64, 8): x = i-block (64 rows), y = head. block 256 = 4 waves (16 rows each).
__global__ __launch_bounds__(256) void k_gemm1(
        const ushort_t* __restrict__ xh, const ushort_t* __restrict__ xl,
        const ushort_t* __restrict__ Wh, const ushort_t* __restrict__ Wl,
        const float* __restrict__ aatt,
        ushort_t* __restrict__ hT,
        float* __restrict__ ssrc2, float* __restrict__ sdst2){
    const int t = threadIdx.x;
    const int l = t & 63, wv = t >> 6;
    const int lr = l & 15, lg = l >> 4;
    const int ib = blockIdx.x*64 + wv*16;
    const int hd = blockIdx.y;
    const int j0 = hd*64;

    f32x4 acc[4] = {};
    #pragma unroll 2
    for(int ks=0; ks<16; ks++){
        const int kb = ks*32 + lg*8;
        bf16x8 ah = *(const bf16x8*)&xh[(size_t)(ib+lr)*512 + kb];
        bf16x8 al = *(const bf16x8*)&xl[(size_t)(ib+lr)*512 + kb];
        bf16x8 bh[4], bl[4];
        #pragma unroll
        for(int nt=0;nt<4;nt++){
            bh[nt] = *(const bf16x8*)&Wh[(size_t)(j0+nt*16+lr)*512 + kb];
            bl[nt] = *(const bf16x8*)&Wl[(size_t)(j0+nt*16+lr)*512 + kb];
        }
        #pragma unroll
        for(int nt=0;nt<4;nt++){
            acc[nt] = __builtin_amdgcn_mfma_f32_16x16x32_bf16(ah, bh[nt], acc[nt], 0,0,0);
            acc[nt] = __builtin_amdgcn_mfma_f32_16x16x32_bf16(al, bh[nt], acc[nt], 0,0,0);
            acc[nt] = __builtin_amdgcn_mfma_f32_16x16x32_bf16(ah, bl[nt], acc[nt], 0,0,0);
        }
    }
    #pragma unroll
    for(int nt=0;nt<4;nt++){
        const int col = j0 + nt*16 + lr;
        ushort4 o;
        o.x = f2bf(acc[nt][0]); o.y = f2bf(acc[nt][1]);
        o.z = f2bf(acc[nt][2]); o.w = f2bf(acc[nt][3]);
        *(ushort4*)&hT[(size_t)col*NN + ib + lg*4] = o;
    }
    float a1v[4], a2v[4];
    #pragma unroll
    for(int nt=0;nt<4;nt++){
        a1v[nt] = aatt[hd*128 + nt*16 + lr];
        a2v[nt] = aatt[hd*128 + 64 + nt*16 + lr];
    }
    #pragma unroll
    for(int r=0;r<4;r++){
        float ps = acc[0][r]*a1v[0] + acc[1][r]*a1v[1] + acc[2][r]*a1v[2] + acc[3][r]*a1v[3];
        float pd = acc[0][r]*a2v[0] + acc[1][r]*a2v[1] + acc[2][r]*a2v[2] + acc[3][r]*a2v[3];
        #pragma unroll
        for(int m=1;m<16;m<<=1){
            ps += __shfl_xor(ps, m);
            pd += __shfl_xor(pd, m);
        }
        if (lr == 0){
            ssrc2[hd*NN + ib + lg*4 + r] = ps*LOG2E;
            sdst2[hd*NN + ib + lg*4 + r] = pd*LOG2E;
        }
    }
}

// ---- attention layer1 via MFMA, 2-deep pipeline, jc=1, FUSED reduce+elu.
// grid (64, 8): i-block(64), head. block 512 = 8 waves, each owns 512 j (16 jt).
// LDS tree-reduce (chunked over mh pairs), wave 0 writes hcat hi/lo bf16.
__global__ __launch_bounds__(512, 4) void k_attn1(
        const ushort_t* __restrict__ hT,
        const float* __restrict__ ssrc2, const float* __restrict__ sdst2,
        const uchar_t* __restrict__ abits,
        ushort_t* __restrict__ hch, ushort_t* __restrict__ hcl){
    const int t = threadIdx.x;
    const int l = t & 63, wv = t >> 6;
    const int hd = blockIdx.y;
    const int i0 = blockIdx.x*64;
    const int lr = l & 15, lg = l >> 4;

    f32x4 acc[4][4] = {};   // [mh][nt]
    f32x4 dacc[4] = {};

    float ss[4];
    #pragma unroll
    for(int mh=0;mh<4;mh++)
        ss[mh] = ssrc2[hd*NN + i0 + mh*16 + lr];

    bf16x8 ones;
    #pragma unroll
    for(int e=0;e<8;e++) ones[e] = (__bf16)1.0f;

    const int jwb = wv*512;                 // wave's j base (16 jt of 32)
    const uchar_t* arow[4];
    #pragma unroll
    for(int mh=0;mh<4;mh++)
        arow[mh] = &abits[(size_t)(i0 + mh*16 + lr)*512 + (jwb >> 3)];

    bf16x8 bA[4], bB[4];
    float4 sdaA, sdbA, sdaB, sdbB;
    uint_t bitsA[4], bitsB[4];

#define LOAD1(SFX, JT) { \
    const int jb_ = jwb + (JT)*32 + lg*8; \
    _Pragma("unroll") \
    for(int nt=0;nt<4;nt++) \
        b##SFX[nt] = *(const bf16x8*)&hT[(size_t)(hd*64 + nt*16 + lr)*NN + jb_]; \
    sda##SFX = *(const float4*)&sdst2[hd*NN + jb_]; \
    sdb##SFX = *(const float4*)&sdst2[hd*NN + jb_ + 4]; \
    _Pragma("unroll") \
    for(int mh=0;mh<4;mh++) \
        bits##SFX[mh] = arow[mh][(JT)*4 + lg]; }

#define COMP1(SFX) { \
    float sdv[8] = {sda##SFX.x, sda##SFX.y, sda##SFX.z, sda##SFX.w, \
                    sdb##SFX.x, sdb##SFX.y, sdb##SFX.z, sdb##SFX.w}; \
    _Pragma("unroll") \
    for(int mh=0;mh<4;mh++){ \
        const uint_t bits = bits##SFX[mh]; \
        bf16x8 a; \
        _Pragma("unroll") \
        for(int e=0;e<8;e++){ \
            float s_ = ss[mh] + sdv[e]; \
            float t_ = fmaxf(s_, 0.2f*s_); \
            float w_ = EXP2(t_) * (float)((bits >> e) & 1u); \
            a[e] = (__bf16)w_; \
        } \
        _Pragma("unroll") \
        for(int nt=0;nt<4;nt++) \
            acc[mh][nt] = __builtin_amdgcn_mfma_f32_16x16x32_bf16( \
                a, b##SFX[nt], acc[mh][nt], 0, 0, 0); \
        dacc[mh] = __builtin_amdgcn_mfma_f32_16x16x32_bf16( \
                a, ones, dacc[mh], 0, 0, 0); \
    } }

    LOAD1(A, 0);
    for(int jt=0; jt<16; jt+=2){
        LOAD1(B, jt+1);
        COMP1(A);
        if (jt + 2 < 16) LOAD1(A, jt+2);
        COMP1(B);
    }
#undef LOAD1
#undef COMP1

    // 8-wave LDS tree reduce, chunked over mh pairs (slots: 8 acc + 2 dacc)
    __shared__ f32x4 red[4][10][64];

#define CHUNK_REDUCE(M0) { \
    __syncthreads(); \
    if (wv >= 4){ \
        _Pragma("unroll") \
        for(int m=0;m<2;m++){ \
            _Pragma("unroll") \
            for(int nt=0;nt<4;nt++) red[wv-4][m*4+nt][l] = acc[(M0)+m][nt]; \
            red[wv-4][8+m][l] = dacc[(M0)+m]; \
        } \
    } \
    __syncthreads(); \
    if (wv < 4){ \
        _Pragma("unroll") \
        for(int m=0;m<2;m++){ \
            _Pragma("unroll") \
            for(int nt=0;nt<4;nt++) acc[(M0)+m][nt] += red[wv][m*4+nt][l]; \
            dacc[(M0)+m] += red[wv][8+m][l]; \
        } \
    } \
    __syncthreads(); \
    if (wv == 2 || wv == 3){ \
        _Pragma("unroll") \
        for(int m=0;m<2;m++){ \
            _Pragma("unroll") \
            for(int nt=0;nt<4;nt++) red[wv-2][m*4+nt][l] = acc[(M0)+m][nt]; \
            red[wv-2][8+m][l] = dacc[(M0)+m]; \
        } \
    } \
    __syncthreads(); \
    if (wv < 2){ \
        _Pragma("unroll") \
        for(int m=0;m<2;m++){ \
            _Pragma("unroll") \
            for(int nt=0;nt<4;nt++) acc[(M0)+m][nt] += red[wv][m*4+nt][l]; \
            dacc[(M0)+m] += red[wv][8+m][l]; \
        } \
    } \
    __syncthreads(); \
    if (wv == 1){ \
        _Pragma("unroll") \
        for(int m=0;m<2;m++){ \
            _Pragma("unroll") \
            for(int nt=0;nt<4;nt++) red[0][m*4+nt][l] = acc[(M0)+m][nt]; \
            red[0][8+m][l] = dacc[(M0)+m]; \
        } \
    } \
    __syncthreads(); \
    if (wv == 0){ \
        _Pragma("unroll") \
        for(int m=0;m<2;m++){ \
            const int mh = (M0)+m; \
            _Pragma("unroll") \
            for(int nt=0;nt<4;nt++) acc[mh][nt] += red[0][m*4+nt][l]; \
            dacc[mh] += red[0][8+m][l]; \
            _Pragma("unroll") \
            for(int nt=0;nt<4;nt++){ \
                const int col = hd*64 + nt*16 + lr; \
                _Pragma("unroll") \
                for(int r=0;r<4;r++){ \
                    const int row = i0 + mh*16 + lg*4 + r; \
                    float v_ = elu1(acc[mh][nt][r] / dacc[mh][r]); \
                    ushort_t hi_ = f2bf(v_); \
                    hch[(size_t)row*512 + col] = hi_; \
                    hcl[(size_t)row*512 + col] = f2bf(v_ - bf2f(hi_)); \
                } \
            } \
        } \
    } }

    CHUNK_REDUCE(0);
    CHUNK_REDUCE(2);
#undef CHUNK_REDUCE
}

// ---- gemm2 via MFMA (hi/lo): h2 = hcat @ Wout; emits h2T bf16 + ss2/sd2.
// grid (64): i-block 64 rows, 4 waves (16 rows each). N=32 (2 nt), K=512.
__global__ __launch_bounds__(256) void k_gemm2(
        const ushort_t* __restrict__ hch, const ushort_t* __restrict__ hcl,
        const ushort_t* __restrict__ Wth, const ushort_t* __restrict__ Wtl,
        const float* __restrict__ aout,
        ushort_t* __restrict__ h2T, float* __restrict__ ss2, float* __restrict__ sd2){
    const int t = threadIdx.x;
    const int l = t & 63, wv = t >> 6;
    const int lr = l & 15, lg = l >> 4;
    const int ib = blockIdx.x*64 + wv*16;

    f32x4 acc[2] = {};
    #pragma unroll 2
    for(int ks=0; ks<16; ks++){
        const int kb = ks*32 + lg*8;
        bf16x8 ah = *(const bf16x8*)&hch[(size_t)(ib+lr)*512 + kb];
        bf16x8 al = *(const bf16x8*)&hcl[(size_t)(ib+lr)*512 + kb];
        bf16x8 bh[2], bl[2];
        #pragma unroll
        for(int nt=0;nt<2;nt++){
            bh[nt] = *(const bf16x8*)&Wth[(size_t)(nt*16+lr)*512 + kb];
            bl[nt] = *(const bf16x8*)&Wtl[(size_t)(nt*16+lr)*512 + kb];
        }
        #pragma unroll
        for(int nt=0;nt<2;nt++){
            acc[nt] = __builtin_amdgcn_mfma_f32_16x16x32_bf16(ah, bh[nt], acc[nt], 0,0,0);
            acc[nt] = __builtin_amdgcn_mfma_f32_16x16x32_bf16(al, bh[nt], acc[nt], 0,0,0);
            acc[nt] = __builtin_amdgcn_mfma_f32_16x16x32_bf16(ah, bl[nt], acc[nt], 0,0,0);
        }
    }
    // h2T bf16 writes: col = nt*16+lr, row = ib+lg*4+r
    #pragma unroll
    for(int nt=0;nt<2;nt++)
        #pragma unroll
        for(int r=0;r<4;r++)
            h2T[(size_t)(nt*16+lr)*NN + ib + lg*4 + r] = f2bf(acc[nt][r]);
    // fused scores2: reduce over lr (16 lanes)
    float a1v[2], a2v[2];
    #pragma unroll
    for(int nt=0;nt<2;nt++){
        a1v[nt] = aout[nt*16 + lr];
        a2v[nt] = aout[32 + nt*16 + lr];
    }
    #pragma unroll
    for(int r=0;r<4;r++){
        float ps = acc[0][r]*a1v[0] + acc[1][r]*a1v[1];
        float pd = acc[0][r]*a2v[0] + acc[1][r]*a2v[1];
        #pragma unroll
        for(int m=1;m<16;m<<=1){
            ps += __shfl_xor(ps, m);
            pd += __shfl_xor(pd, m);
        }
        if (lr == 0){
            ss2[ib + lg*4 + r] = ps*LOG2E;
            sd2[ib + lg*4 + r] = pd*LOG2E;
        }
    }
}

// ---- attention layer2 via MFMA, 2-deep pipeline, i-tile 64.
// grid (64, 8): i-block(64), j-chunk(512). 4 waves split chunk (128 j = 4 jt each).
__global__ __launch_bounds__(256) void k_attn2(
        const ushort_t* __restrict__ h2T,
        const float* __restrict__ ss2, const float* __restrict__ sd2,
        const uchar_t* __restrict__ abits,
        float* __restrict__ pnum2T, float* __restrict__ pden2){
    const int t = threadIdx.x;
    const int l = t & 63, wv = t >> 6;
    const int i0 = blockIdx.x*64;
    const int jc = blockIdx.y;
    const int lr = l & 15, lg = l >> 4;

    f32x4 acc[4][2] = {};   // [mh][nt]
    f32x4 dacc[4] = {};

    float ss[4];
    #pragma unroll
    for(int mh=0;mh<4;mh++)
        ss[mh] = ss2[i0 + mh*16 + lr];

    bf16x8 ones;
    #pragma unroll
    for(int e=0;e<8;e++) ones[e] = (__bf16)1.0f;

    const int jwb = jc*512 + wv*128;          // 4 jt of 32
    const uchar_t* arow[4];
    #pragma unroll
    for(int mh=0;mh<4;mh++)
        arow[mh] = &abits[(size_t)(i0 + mh*16 + lr)*512 + (jwb >> 3)];

    bf16x8 bA[2], bB[2];
    float4 sdaA, sdbA, sdaB, sdbB;
    uint_t bitsA[4], bitsB[4];

#define LOAD2(SFX, JT) { \
    const int jb_ = jwb + (JT)*32 + lg*8; \
    _Pragma("unroll") \
    for(int nt=0;nt<2;nt++) \
        b##SFX[nt] = *(const bf16x8*)&h2T[(size_t)(nt*16 + lr)*NN + jb_]; \
    sda##SFX = *(const float4*)&sd2[jb_]; \
    sdb##SFX = *(const float4*)&sd2[jb_ + 4]; \
    _Pragma("unroll") \
    for(int mh=0;mh<4;mh++) \
        bits##SFX[mh] = arow[mh][(JT)*4 + lg]; }

#define COMP2(SFX) { \
    float sdv[8] = {sda##SFX.x, sda##SFX.y, sda##SFX.z, sda##SFX.w, \
                    sdb##SFX.x, sdb##SFX.y, sdb##SFX.z, sdb##SFX.w}; \
    _Pragma("unroll") \
    for(int mh=0;mh<4;mh++){ \
        const uint_t bits = bits##SFX[mh]; \
        bf16x8 a; \
        _Pragma("unroll") \
        for(int e=0;e<8;e++){ \
            float s_ = ss[mh] + sdv[e]; \
            float t_ = fmaxf(s_, 0.2f*s_); \
            float w_ = EXP2(t_) * (float)((bits >> e) & 1u); \
            a[e] = (__bf16)w_; \
        } \
        _Pragma("unroll") \
        for(int nt=0;nt<2;nt++) \
            acc[mh][nt] = __builtin_amdgcn_mfma_f32_16x16x32_bf16( \
                a, b##SFX[nt], acc[mh][nt], 0, 0, 0); \
        dacc[mh] = __builtin_amdgcn_mfma_f32_16x16x32_bf16( \
                a, ones, dacc[mh], 0, 0, 0); \
    } }

    LOAD2(A, 0);
    for(int jt=0; jt<4; jt+=2){
        LOAD2(B, jt+1);
        COMP2(A);
        if (jt + 2 < 4) LOAD2(A, jt+2);
        COMP2(B);
    }
#undef LOAD2
#undef COMP2

    // cross-wave LDS reduce: slots 0..7 acc[mh*2+nt], 8..11 dacc[mh]
    __shared__ f32x4 red2[2][12][64];
    __syncthreads();
    if (wv >= 2){
        #pragma unroll
        for(int mh=0;mh<4;mh++){
            #pragma unroll
            for(int nt=0;nt<2;nt++) red2[wv-2][mh*2+nt][l] = acc[mh][nt];
            red2[wv-2][8+mh][l] = dacc[mh];
        }
    }
    __syncthreads();
    if (wv < 2){
        #pragma unroll
        for(int mh=0;mh<4;mh++){
            #pragma unroll
            for(int nt=0;nt<2;nt++) acc[mh][nt] += red2[wv][mh*2+nt][l];
            dacc[mh] += red2[wv][8+mh][l];
        }
    }
    __syncthreads();
    if (wv == 1){
        #pragma unroll
        for(int mh=0;mh<4;mh++){
            #pragma unroll
            for(int nt=0;nt<2;nt++) red2[0][mh*2+nt][l] = acc[mh][nt];
            red2[0][8+mh][l] = dacc[mh];
        }
    }
    __syncthreads();
    if (wv == 0){
        #pragma unroll
        for(int mh=0;mh<4;mh++){
            #pragma unroll
            for(int nt=0;nt<2;nt++){
                f32x4 v = acc[mh][nt] + red2[0][mh*2+nt][l];
                int col = nt*16 + lr;
                float4 o = {v[0], v[1], v[2], v[3]};
                *(float4*)&pnum2T[((size_t)jc*32 + col)*NN + i0 + mh*16 + lg*4] = o;
            }
            f32x4 d = dacc[mh] + red2[0][8+mh][l];
            if (lr == 0){
                #pragma unroll
                for(int r=0;r<4;r++)
                    pden2[(size_t)jc*NN + i0 + mh*16 + lg*4 + r] = d[r];
            }
        }
    }
}

// ---- reduce layer2 -> final output (vectorized reads over i)
__global__ void k_reduce2(const float* __restrict__ pnum2T, const float* __restrict__ pden2,
                          float* __restrict__ out){
    int idx = blockIdx.x*256 + threadIdx.x;       // < 32*1024
    int c = idx >> 10, i4 = (idx & 1023)*4;
    f32x4 s = {}, d = {};
    #pragma unroll
    for(int jc=0;jc<8;jc++){
        s += *(const f32x4*)&pnum2T[((size_t)jc*32 + c)*NN + i4];
        d += *(const f32x4*)&pden2[(size_t)jc*NN + i4];
    }
    #pragma unroll
    for(int r=0;r<4;r++)
        out[(size_t)(i4+r)*32 + c] = elu1(s[r]/d[r]);
}

extern "C" void kernel_launch(void* const* d_in, const int* in_sizes, int n_in,
                              void* d_out, int out_size, void* d_ws, size_t ws_size,
                              hipStream_t stream){
    const float* x    = (const float*)d_in[0];
    const int*   adj  = (const int*)  d_in[1];
    const float* Watt = (const float*)d_in[2];
    const float* aatt = (const float*)d_in[3];
    const float* Wout = (const float*)d_in[4];
    const float* aout = (const float*)d_in[5];
    float* out = (float*)d_out;
    char* ws = (char*)d_ws;

    ushort_t* hch   = (ushort_t*)(ws + (size_t) 0*MB);  // 4 MB [4096][512] bf16 hi
    ushort_t* hcl   = (ushort_t*)(ws + (size_t) 4*MB);  // 4 MB lo
    ushort_t* Whi   = (ushort_t*)(ws + (size_t) 8*MB);  // 512 KB [512][512]
    ushort_t* Wlo   = (ushort_t*)(ws + (size_t) 8*MB + 512*1024);
    float*    ssrc2 = (float*)   (ws + (size_t) 9*MB);  // 128 KB [8][4096]
    float*    sdst2 = (float*)   (ws + (size_t)10*MB);  // 128 KB
    ushort_t* hT    = (ushort_t*)(ws + (size_t)11*MB);  // 4 MB [512][4096]
    uint_t*   abits = (uint_t*)  (ws + (size_t)15*MB);  // 2 MB [4096][128]
    ushort_t* Wth   = (ushort_t*)(ws + (size_t)17*MB);  // 32 KB [32][512]
    ushort_t* Wtl   = (ushort_t*)(ws + (size_t)17*MB + 64*1024);
    float*    ss2   = (float*)   (ws + (size_t)18*MB);  // 16 KB
    float*    sd2   = (float*)   (ws + (size_t)19*MB);  // 16 KB
    ushort_t* h2T   = (ushort_t*)(ws + (size_t)20*MB);  // 256 KB [32][4096]
    float*    pden2 = (float*)   (ws + (size_t)21*MB);  // 128 KB [8][4096]
    float*    pnum2T= (float*)   (ws + (size_t)22*MB);  // 4 MB [8][32][4096]
    ushort_t* xh    = (ushort_t*)(ws + (size_t)26*MB);  // 4 MB [4096][512]
    ushort_t* xl    = (ushort_t*)(ws + (size_t)30*MB);  // 4 MB
    if (ws_size < (size_t)40*MB) return;

    k_prep    <<<272, 256, 0, stream>>>(Watt, Wout, Whi, Wlo, Wth, Wtl);
    k_splitx  <<<2048, 256, 0, stream>>>(x, xh, xl);
    k_pack    <<<2048, 256, 0, stream>>>(adj, abits);
    k_gemm1   <<<dim3(64,8), 256, 0, stream>>>(xh, xl, Whi, Wlo, aatt, hT, ssrc2, sdst2);
    k_attn1   <<<dim3(64,8), 512, 0, stream>>>(hT, ssrc2, sdst2, (const uchar_t*)abits, hch, hcl);
    k_gemm2   <<<64, 256, 0, stream>>>(hch, hcl, Wth, Wtl, aout, h2T, ss2, sd2);
    k_attn2   <<<dim3(64,8), 256, 0, stream>>>(h2T, ss2, sd2, (const uchar_t*)abits, pnum2T, pden2);
    k_reduce2 <<<128, 256, 0, stream>>>(pnum2T, pden2, out);
}

// Round 9
// 257.786 us; speedup vs baseline: 1.5868x; 1.5868x over previous
//
#include <hip/hip_runtime.h>
#include <math.h>

#define NN 4096      // nodes
#define CC 512       // concat dim = 8 heads * 64
#define MB (1024*1024)
#define LOG2E 1.4426950408889634f

typedef __attribute__((ext_vector_type(8))) __bf16 bf16x8;
typedef __attribute__((ext_vector_type(4))) float f32x4;
typedef unsigned short ushort_t;
typedef unsigned int uint_t;
typedef unsigned char uchar_t;

#if __has_builtin(__builtin_amdgcn_exp2f)
#define EXP2(x) __builtin_amdgcn_exp2f(x)
#else
#define EXP2(x) exp2f(x)
#endif

static __device__ __forceinline__ float elu1(float x){ return x > 0.f ? x : (__expf(x)-1.f); }
static __device__ __forceinline__ ushort_t f2bf(float f){
    union { float f; uint_t u; } v; v.f = f;
    uint_t r = (v.u + 0x7FFFu + ((v.u >> 16) & 1u)) >> 16;
    return (ushort_t)r;
}
static __device__ __forceinline__ float bf2f(ushort_t h){
    union { uint_t u; float f; } q; q.u = ((uint_t)h) << 16; return q.f;
}

// ---- prep: W_att [8][512(k)][64(f)] -> Wh/Wl [512(c)][512(k)] bf16 hi/lo
//           Wout [512(k)][32(n)] -> WoutT_h/l [32(n)][512(k)] bf16 hi/lo
__global__ void k_prep(const float* __restrict__ Watt, const float* __restrict__ Wout,
                       ushort_t* __restrict__ Wh, ushort_t* __restrict__ Wl,
                       ushort_t* __restrict__ Wth, ushort_t* __restrict__ Wtl){
    int idx = blockIdx.x*256 + threadIdx.x;
    if (idx < 512*128){
        int c = idx >> 7, kq = idx & 127, k = kq*4;
        ushort4 h4, l4;
        float v[4];
        #pragma unroll
        for(int j=0;j<4;j++)
            v[j] = Watt[(c>>6)*(512*64) + (k+j)*64 + (c&63)];
        h4.x = f2bf(v[0]); h4.y = f2bf(v[1]); h4.z = f2bf(v[2]); h4.w = f2bf(v[3]);
        l4.x = f2bf(v[0]-bf2f(h4.x)); l4.y = f2bf(v[1]-bf2f(h4.y));
        l4.z = f2bf(v[2]-bf2f(h4.z)); l4.w = f2bf(v[3]-bf2f(h4.w));
        *(ushort4*)&Wh[(size_t)c*512 + k] = h4;
        *(ushort4*)&Wl[(size_t)c*512 + k] = l4;
    } else if (idx < 512*128 + 32*128){
        int idx2 = idx - 512*128;
        int n = idx2 >> 7, kq = idx2 & 127, k = kq*4;
        ushort4 h4, l4;
        float v[4];
        #pragma unroll
        for(int j=0;j<4;j++)
            v[j] = Wout[(size_t)(k+j)*32 + n];
        h4.x = f2bf(v[0]); h4.y = f2bf(v[1]); h4.z = f2bf(v[2]); h4.w = f2bf(v[3]);
        l4.x = f2bf(v[0]-bf2f(h4.x)); l4.y = f2bf(v[1]-bf2f(h4.y));
        l4.z = f2bf(v[2]-bf2f(h4.z)); l4.w = f2bf(v[3]-bf2f(h4.w));
        *(ushort4*)&Wth[(size_t)n*512 + k] = h4;
        *(ushort4*)&Wtl[(size_t)n*512 + k] = l4;
    }
}

// ---- split x [4096][512] f32 -> xh/xl bf16
__global__ void k_splitx(const float* __restrict__ x,
                         ushort_t* __restrict__ xh, ushort_t* __restrict__ xl){
    int idx = blockIdx.x*256 + threadIdx.x;     // < 4096*512/4
    float4 v = *(const float4*)&x[(size_t)idx*4];
    ushort4 h4, l4;
    h4.x = f2bf(v.x); h4.y = f2bf(v.y); h4.z = f2bf(v.z); h4.w = f2bf(v.w);
    l4.x = f2bf(v.x-bf2f(h4.x)); l4.y = f2bf(v.y-bf2f(h4.y));
    l4.z = f2bf(v.z-bf2f(h4.z)); l4.w = f2bf(v.w-bf2f(h4.w));
    *(ushort4*)&xh[(size_t)idx*4] = h4;
    *(ushort4*)&xl[(size_t)idx*4] = l4;
}

// ---- pack adjacency to bits
__global__ void k_pack(const int* __restrict__ adj, uint_t* __restrict__ abits){
    int idx = blockIdx.x*256 + threadIdx.x;            // < 4096*128
    int i = idx >> 7, q = idx & 127;
    const int4* p = (const int4*)&adj[(size_t)i*NN + q*32];
    uint_t m = 0;
    #pragma unroll
    for(int g=0; g<8; g++){
        int4 v = p[g];
        m |= (uint_t)(v.x > 0) << (g*4 + 0);
        m |= (uint_t)(v.y > 0) << (g*4 + 1);
        m |= (uint_t)(v.z > 0) << (g*4 + 2);
        m |= (uint_t)(v.w > 0) << (g*4 + 3);
    }
    abits[idx] = m;
}

// ---- gemm1 via MFMA (bf16 hi/lo split): h = x @ W_all, FUSED scores1.
// grid (64, 8): x = i-block (64 rows), y = head. block 256 = 4 waves (16 rows each).
__global__ __launch_bounds__(256) void k_gemm1(
        const ushort_t* __restrict__ xh, const ushort_t* __restrict__ xl,
        const ushort_t* __restrict__ Wh, const ushort_t* __restrict__ Wl,
        const float* __restrict__ aatt,
        ushort_t* __restrict__ hT,
        float* __restrict__ ssrc2, float* __restrict__ sdst2){
    const int t = threadIdx.x;
    const int l = t & 63, wv = t >> 6;
    const int lr = l & 15, lg = l >> 4;
    const int ib = blockIdx.x*64 + wv*16;
    const int hd = blockIdx.y;
    const int j0 = hd*64;

    f32x4 acc[4] = {};
    #pragma unroll 2
    for(int ks=0; ks<16; ks++){
        const int kb = ks*32 + lg*8;
        bf16x8 ah = *(const bf16x8*)&xh[(size_t)(ib+lr)*512 + kb];
        bf16x8 al = *(const bf16x8*)&xl[(size_t)(ib+lr)*512 + kb];
        bf16x8 bh[4], bl[4];
        #pragma unroll
        for(int nt=0;nt<4;nt++){
            bh[nt] = *(const bf16x8*)&Wh[(size_t)(j0+nt*16+lr)*512 + kb];
            bl[nt] = *(const bf16x8*)&Wl[(size_t)(j0+nt*16+lr)*512 + kb];
        }
        #pragma unroll
        for(int nt=0;nt<4;nt++){
            acc[nt] = __builtin_amdgcn_mfma_f32_16x16x32_bf16(ah, bh[nt], acc[nt], 0,0,0);
            acc[nt] = __builtin_amdgcn_mfma_f32_16x16x32_bf16(al, bh[nt], acc[nt], 0,0,0);
            acc[nt] = __builtin_amdgcn_mfma_f32_16x16x32_bf16(ah, bl[nt], acc[nt], 0,0,0);
        }
    }
    #pragma unroll
    for(int nt=0;nt<4;nt++){
        const int col = j0 + nt*16 + lr;
        ushort4 o;
        o.x = f2bf(acc[nt][0]); o.y = f2bf(acc[nt][1]);
        o.z = f2bf(acc[nt][2]); o.w = f2bf(acc[nt][3]);
        *(ushort4*)&hT[(size_t)col*NN + ib + lg*4] = o;
    }
    float a1v[4], a2v[4];
    #pragma unroll
    for(int nt=0;nt<4;nt++){
        a1v[nt] = aatt[hd*128 + nt*16 + lr];
        a2v[nt] = aatt[hd*128 + 64 + nt*16 + lr];
    }
    #pragma unroll
    for(int r=0;r<4;r++){
        float ps = acc[0][r]*a1v[0] + acc[1][r]*a1v[1] + acc[2][r]*a1v[2] + acc[3][r]*a1v[3];
        float pd = acc[0][r]*a2v[0] + acc[1][r]*a2v[1] + acc[2][r]*a2v[2] + acc[3][r]*a2v[3];
        #pragma unroll
        for(int m=1;m<16;m<<=1){
            ps += __shfl_xor(ps, m);
            pd += __shfl_xor(pd, m);
        }
        if (lr == 0){
            ssrc2[hd*NN + ib + lg*4 + r] = ps*LOG2E;
            sdst2[hd*NN + ib + lg*4 + r] = pd*LOG2E;
        }
    }
}

// ---- attention layer1 via MFMA, 2-deep pipeline, jc=1, FUSED reduce+elu.
// grid (64, 8): i-block(64), head. block 512 = 8 waves, each owns 512 j (16 jt).
// LDS tree-reduce (chunked over mh pairs), wave 0 writes hcat hi/lo bf16.
// NOTE: launch_bounds (512, 2): 2 waves/EU min -> VGPR cap 256 (R7's (512,4)
// capped VGPR at 64 -> 661MB scratch spill -> 3x regression).
__global__ __launch_bounds__(512, 2) void k_attn1(
        const ushort_t* __restrict__ hT,
        const float* __restrict__ ssrc2, const float* __restrict__ sdst2,
        const uchar_t* __restrict__ abits,
        ushort_t* __restrict__ hch, ushort_t* __restrict__ hcl){
    const int t = threadIdx.x;
    const int l = t & 63, wv = t >> 6;
    const int hd = blockIdx.y;
    const int i0 = blockIdx.x*64;
    const int lr = l & 15, lg = l >> 4;

    f32x4 acc[4][4] = {};   // [mh][nt]
    f32x4 dacc[4] = {};

    float ss[4];
    #pragma unroll
    for(int mh=0;mh<4;mh++)
        ss[mh] = ssrc2[hd*NN + i0 + mh*16 + lr];

    bf16x8 ones;
    #pragma unroll
    for(int e=0;e<8;e++) ones[e] = (__bf16)1.0f;

    const int jwb = wv*512;                 // wave's j base (16 jt of 32)
    const uchar_t* arow[4];
    #pragma unroll
    for(int mh=0;mh<4;mh++)
        arow[mh] = &abits[(size_t)(i0 + mh*16 + lr)*512 + (jwb >> 3)];

    bf16x8 bA[4], bB[4];
    float4 sdaA, sdbA, sdaB, sdbB;
    uint_t bitsA[4], bitsB[4];

#define LOAD1(SFX, JT) { \
    const int jb_ = jwb + (JT)*32 + lg*8; \
    _Pragma("unroll") \
    for(int nt=0;nt<4;nt++) \
        b##SFX[nt] = *(const bf16x8*)&hT[(size_t)(hd*64 + nt*16 + lr)*NN + jb_]; \
    sda##SFX = *(const float4*)&sdst2[hd*NN + jb_]; \
    sdb##SFX = *(const float4*)&sdst2[hd*NN + jb_ + 4]; \
    _Pragma("unroll") \
    for(int mh=0;mh<4;mh++) \
        bits##SFX[mh] = arow[mh][(JT)*4 + lg]; }

#define COMP1(SFX) { \
    float sdv[8] = {sda##SFX.x, sda##SFX.y, sda##SFX.z, sda##SFX.w, \
                    sdb##SFX.x, sdb##SFX.y, sdb##SFX.z, sdb##SFX.w}; \
    _Pragma("unroll") \
    for(int mh=0;mh<4;mh++){ \
        const uint_t bits = bits##SFX[mh]; \
        bf16x8 a; \
        _Pragma("unroll") \
        for(int e=0;e<8;e++){ \
            float s_ = ss[mh] + sdv[e]; \
            float t_ = fmaxf(s_, 0.2f*s_); \
            float w_ = EXP2(t_) * (float)((bits >> e) & 1u); \
            a[e] = (__bf16)w_; \
        } \
        _Pragma("unroll") \
        for(int nt=0;nt<4;nt++) \
            acc[mh][nt] = __builtin_amdgcn_mfma_f32_16x16x32_bf16( \
                a, b##SFX[nt], acc[mh][nt], 0, 0, 0); \
        dacc[mh] = __builtin_amdgcn_mfma_f32_16x16x32_bf16( \
                a, ones, dacc[mh], 0, 0, 0); \
    } }

    LOAD1(A, 0);
    for(int jt=0; jt<16; jt+=2){
        LOAD1(B, jt+1);
        COMP1(A);
        if (jt + 2 < 16) LOAD1(A, jt+2);
        COMP1(B);
    }
#undef LOAD1
#undef COMP1

    // 8-wave LDS tree reduce, chunked over mh pairs (slots: 8 acc + 2 dacc)
    __shared__ f32x4 red[4][10][64];

#define CHUNK_REDUCE(M0) { \
    __syncthreads(); \
    if (wv >= 4){ \
        _Pragma("unroll") \
        for(int m=0;m<2;m++){ \
            _Pragma("unroll") \
            for(int nt=0;nt<4;nt++) red[wv-4][m*4+nt][l] = acc[(M0)+m][nt]; \
            red[wv-4][8+m][l] = dacc[(M0)+m]; \
        } \
    } \
    __syncthreads(); \
    if (wv < 4){ \
        _Pragma("unroll") \
        for(int m=0;m<2;m++){ \
            _Pragma("unroll") \
            for(int nt=0;nt<4;nt++) acc[(M0)+m][nt] += red[wv][m*4+nt][l]; \
            dacc[(M0)+m] += red[wv][8+m][l]; \
        } \
    } \
    __syncthreads(); \
    if (wv == 2 || wv == 3){ \
        _Pragma("unroll") \
        for(int m=0;m<2;m++){ \
            _Pragma("unroll") \
            for(int nt=0;nt<4;nt++) red[wv-2][m*4+nt][l] = acc[(M0)+m][nt]; \
            red[wv-2][8+m][l] = dacc[(M0)+m]; \
        } \
    } \
    __syncthreads(); \
    if (wv < 2){ \
        _Pragma("unroll") \
        for(int m=0;m<2;m++){ \
            _Pragma("unroll") \
            for(int nt=0;nt<4;nt++) acc[(M0)+m][nt] += red[wv][m*4+nt][l]; \
            dacc[(M0)+m] += red[wv][8+m][l]; \
        } \
    } \
    __syncthreads(); \
    if (wv == 1){ \
        _Pragma("unroll") \
        for(int m=0;m<2;m++){ \
            _Pragma("unroll") \
            for(int nt=0;nt<4;nt++) red[0][m*4+nt][l] = acc[(M0)+m][nt]; \
            red[0][8+m][l] = dacc[(M0)+m]; \
        } \
    } \
    __syncthreads(); \
    if (wv == 0){ \
        _Pragma("unroll") \
        for(int m=0;m<2;m++){ \
            const int mh = (M0)+m; \
            _Pragma("unroll") \
            for(int nt=0;nt<4;nt++) acc[mh][nt] += red[0][m*4+nt][l]; \
            dacc[mh] += red[0][8+m][l]; \
            _Pragma("unroll") \
            for(int nt=0;nt<4;nt++){ \
                const int col = hd*64 + nt*16 + lr; \
                _Pragma("unroll") \
                for(int r=0;r<4;r++){ \
                    const int row = i0 + mh*16 + lg*4 + r; \
                    float v_ = elu1(acc[mh][nt][r] / dacc[mh][r]); \
                    ushort_t hi_ = f2bf(v_); \
                    hch[(size_t)row*512 + col] = hi_; \
                    hcl[(size_t)row*512 + col] = f2bf(v_ - bf2f(hi_)); \
                } \
            } \
        } \
    } }

    CHUNK_REDUCE(0);
    CHUNK_REDUCE(2);
#undef CHUNK_REDUCE
}

// ---- gemm2 via MFMA (hi/lo): h2 = hcat @ Wout; emits h2T bf16 + ss2/sd2.
// grid (64): i-block 64 rows, 4 waves (16 rows each). N=32 (2 nt), K=512.
__global__ __launch_bounds__(256) void k_gemm2(
        const ushort_t* __restrict__ hch, const ushort_t* __restrict__ hcl,
        const ushort_t* __restrict__ Wth, const ushort_t* __restrict__ Wtl,
        const float* __restrict__ aout,
        ushort_t* __restrict__ h2T, float* __restrict__ ss2, float* __restrict__ sd2){
    const int t = threadIdx.x;
    const int l = t & 63, wv = t >> 6;
    const int lr = l & 15, lg = l >> 4;
    const int ib = blockIdx.x*64 + wv*16;

    f32x4 acc[2] = {};
    #pragma unroll 2
    for(int ks=0; ks<16; ks++){
        const int kb = ks*32 + lg*8;
        bf16x8 ah = *(const bf16x8*)&hch[(size_t)(ib+lr)*512 + kb];
        bf16x8 al = *(const bf16x8*)&hcl[(size_t)(ib+lr)*512 + kb];
        bf16x8 bh[2], bl[2];
        #pragma unroll
        for(int nt=0;nt<2;nt++){
            bh[nt] = *(const bf16x8*)&Wth[(size_t)(nt*16+lr)*512 + kb];
            bl[nt] = *(const bf16x8*)&Wtl[(size_t)(nt*16+lr)*512 + kb];
        }
        #pragma unroll
        for(int nt=0;nt<2;nt++){
            acc[nt] = __builtin_amdgcn_mfma_f32_16x16x32_bf16(ah, bh[nt], acc[nt], 0,0,0);
            acc[nt] = __builtin_amdgcn_mfma_f32_16x16x32_bf16(al, bh[nt], acc[nt], 0,0,0);
            acc[nt] = __builtin_amdgcn_mfma_f32_16x16x32_bf16(ah, bl[nt], acc[nt], 0,0,0);
        }
    }
    // h2T bf16 writes: col = nt*16+lr, row = ib+lg*4+r
    #pragma unroll
    for(int nt=0;nt<2;nt++)
        #pragma unroll
        for(int r=0;r<4;r++)
            h2T[(size_t)(nt*16+lr)*NN + ib + lg*4 + r] = f2bf(acc[nt][r]);
    // fused scores2: reduce over lr (16 lanes)
    float a1v[2], a2v[2];
    #pragma unroll
    for(int nt=0;nt<2;nt++){
        a1v[nt] = aout[nt*16 + lr];
        a2v[nt] = aout[32 + nt*16 + lr];
    }
    #pragma unroll
    for(int r=0;r<4;r++){
        float ps = acc[0][r]*a1v[0] + acc[1][r]*a1v[1];
        float pd = acc[0][r]*a2v[0] + acc[1][r]*a2v[1];
        #pragma unroll
        for(int m=1;m<16;m<<=1){
            ps += __shfl_xor(ps, m);
            pd += __shfl_xor(pd, m);
        }
        if (lr == 0){
            ss2[ib + lg*4 + r] = ps*LOG2E;
            sd2[ib + lg*4 + r] = pd*LOG2E;
        }
    }
}

// ---- attention layer2 via MFMA, 2-deep pipeline, i-tile 64.
// grid (64, 8): i-block(64), j-chunk(512). 4 waves split chunk (128 j = 4 jt each).
__global__ __launch_bounds__(256) void k_attn2(
        const ushort_t* __restrict__ h2T,
        const float* __restrict__ ss2, const float* __restrict__ sd2,
        const uchar_t* __restrict__ abits,
        float* __restrict__ pnum2T, float* __restrict__ pden2){
    const int t = threadIdx.x;
    const int l = t & 63, wv = t >> 6;
    const int i0 = blockIdx.x*64;
    const int jc = blockIdx.y;
    const int lr = l & 15, lg = l >> 4;

    f32x4 acc[4][2] = {};   // [mh][nt]
    f32x4 dacc[4] = {};

    float ss[4];
    #pragma unroll
    for(int mh=0;mh<4;mh++)
        ss[mh] = ss2[i0 + mh*16 + lr];

    bf16x8 ones;
    #pragma unroll
    for(int e=0;e<8;e++) ones[e] = (__bf16)1.0f;

    const int jwb = jc*512 + wv*128;          // 4 jt of 32
    const uchar_t* arow[4];
    #pragma unroll
    for(int mh=0;mh<4;mh++)
        arow[mh] = &abits[(size_t)(i0 + mh*16 + lr)*512 + (jwb >> 3)];

    bf16x8 bA[2], bB[2];
    float4 sdaA, sdbA, sdaB, sdbB;
    uint_t bitsA[4], bitsB[4];

#define LOAD2(SFX, JT) { \
    const int jb_ = jwb + (JT)*32 + lg*8; \
    _Pragma("unroll") \
    for(int nt=0;nt<2;nt++) \
        b##SFX[nt] = *(const bf16x8*)&h2T[(size_t)(nt*16 + lr)*NN + jb_]; \
    sda##SFX = *(const float4*)&sd2[jb_]; \
    sdb##SFX = *(const float4*)&sd2[jb_ + 4]; \
    _Pragma("unroll") \
    for(int mh=0;mh<4;mh++) \
        bits##SFX[mh] = arow[mh][(JT)*4 + lg]; }

#define COMP2(SFX) { \
    float sdv[8] = {sda##SFX.x, sda##SFX.y, sda##SFX.z, sda##SFX.w, \
                    sdb##SFX.x, sdb##SFX.y, sdb##SFX.z, sdb##SFX.w}; \
    _Pragma("unroll") \
    for(int mh=0;mh<4;mh++){ \
        const uint_t bits = bits##SFX[mh]; \
        bf16x8 a; \
        _Pragma("unroll") \
        for(int e=0;e<8;e++){ \
            float s_ = ss[mh] + sdv[e]; \
            float t_ = fmaxf(s_, 0.2f*s_); \
            float w_ = EXP2(t_) * (float)((bits >> e) & 1u); \
            a[e] = (__bf16)w_; \
        } \
        _Pragma("unroll") \
        for(int nt=0;nt<2;nt++) \
            acc[mh][nt] = __builtin_amdgcn_mfma_f32_16x16x32_bf16( \
                a, b##SFX[nt], acc[mh][nt], 0, 0, 0); \
        dacc[mh] = __builtin_amdgcn_mfma_f32_16x16x32_bf16( \
                a, ones, dacc[mh], 0, 0, 0); \
    } }

    LOAD2(A, 0);
    for(int jt=0; jt<4; jt+=2){
        LOAD2(B, jt+1);
        COMP2(A);
        if (jt + 2 < 4) LOAD2(A, jt+2);
        COMP2(B);
    }
#undef LOAD2
#undef COMP2

    // cross-wave LDS reduce: slots 0..7 acc[mh*2+nt], 8..11 dacc[mh]
    __shared__ f32x4 red2[2][12][64];
    __syncthreads();
    if (wv >= 2){
        #pragma unroll
        for(int mh=0;mh<4;mh++){
            #pragma unroll
            for(int nt=0;nt<2;nt++) red2[wv-2][mh*2+nt][l] = acc[mh][nt];
            red2[wv-2][8+mh][l] = dacc[mh];
        }
    }
    __syncthreads();
    if (wv < 2){
        #pragma unroll
        for(int mh=0;mh<4;mh++){
            #pragma unroll
            for(int nt=0;nt<2;nt++) acc[mh][nt] += red2[wv][mh*2+nt][l];
            dacc[mh] += red2[wv][8+mh][l];
        }
    }
    __syncthreads();
    if (wv == 1){
        #pragma unroll
        for(int mh=0;mh<4;mh++){
            #pragma unroll
            for(int nt=0;nt<2;nt++) red2[0][mh*2+nt][l] = acc[mh][nt];
            red2[0][8+mh][l] = dacc[mh];
        }
    }
    __syncthreads();
    if (wv == 0){
        #pragma unroll
        for(int mh=0;mh<4;mh++){
            #pragma unroll
            for(int nt=0;nt<2;nt++){
                f32x4 v = acc[mh][nt] + red2[0][mh*2+nt][l];
                int col = nt*16 + lr;
                float4 o = {v[0], v[1], v[2], v[3]};
                *(float4*)&pnum2T[((size_t)jc*32 + col)*NN + i0 + mh*16 + lg*4] = o;
            }
            f32x4 d = dacc[mh] + red2[0][8+mh][l];
            if (lr == 0){
                #pragma unroll
                for(int r=0;r<4;r++)
                    pden2[(size_t)jc*NN + i0 + mh*16 + lg*4 + r] = d[r];
            }
        }
    }
}

// ---- reduce layer2 -> final output (vectorized reads over i)
__global__ void k_reduce2(const float* __restrict__ pnum2T, const float* __restrict__ pden2,
                          float* __restrict__ out){
    int idx = blockIdx.x*256 + threadIdx.x;       // < 32*1024
    int c = idx >> 10, i4 = (idx & 1023)*4;
    f32x4 s = {}, d = {};
    #pragma unroll
    for(int jc=0;jc<8;jc++){
        s += *(const f32x4*)&pnum2T[((size_t)jc*32 + c)*NN + i4];
        d += *(const f32x4*)&pden2[(size_t)jc*NN + i4];
    }
    #pragma unroll
    for(int r=0;r<4;r++)
        out[(size_t)(i4+r)*32 + c] = elu1(s[r]/d[r]);
}

extern "C" void kernel_launch(void* const* d_in, const int* in_sizes, int n_in,
                              void* d_out, int out_size, void* d_ws, size_t ws_size,
                              hipStream_t stream){
    const float* x    = (const float*)d_in[0];
    const int*   adj  = (const int*)  d_in[1];
    const float* Watt = (const float*)d_in[2];
    const float* aatt = (const float*)d_in[3];
    const float* Wout = (const float*)d_in[4];
    const float* aout = (const float*)d_in[5];
    float* out = (float*)d_out;
    char* ws = (char*)d_ws;

    ushort_t* hch   = (ushort_t*)(ws + (size_t) 0*MB);  // 4 MB [4096][512] bf16 hi
    ushort_t* hcl   = (ushort_t*)(ws + (size_t) 4*MB);  // 4 MB lo
    ushort_t* Whi   = (ushort_t*)(ws + (size_t) 8*MB);  // 512 KB [512][512]
    ushort_t* Wlo   = (ushort_t*)(ws + (size_t) 8*MB + 512*1024);
    float*    ssrc2 = (float*)   (ws + (size_t) 9*MB);  // 128 KB [8][4096]
    float*    sdst2 = (float*)   (ws + (size_t)10*MB);  // 128 KB
    ushort_t* hT    = (ushort_t*)(ws + (size_t)11*MB);  // 4 MB [512][4096]
    uint_t*   abits = (uint_t*)  (ws + (size_t)15*MB);  // 2 MB [4096][128]
    ushort_t* Wth   = (ushort_t*)(ws + (size_t)17*MB);  // 32 KB [32][512]
    ushort_t* Wtl   = (ushort_t*)(ws + (size_t)17*MB + 64*1024);
    float*    ss2   = (float*)   (ws + (size_t)18*MB);  // 16 KB
    float*    sd2   = (float*)   (ws + (size_t)19*MB);  // 16 KB
    ushort_t* h2T   = (ushort_t*)(ws + (size_t)20*MB);  // 256 KB [32][4096]
    float*    pden2 = (float*)   (ws + (size_t)21*MB);  // 128 KB [8][4096]
    float*    pnum2T= (float*)   (ws + (size_t)22*MB);  // 4 MB [8][32][4096]
    ushort_t* xh    = (ushort_t*)(ws + (size_t)26*MB);  // 4 MB [4096][512]
    ushort_t* xl    = (ushort_t*)(ws + (size_t)30*MB);  // 4 MB
    if (ws_size < (size_t)40*MB) return;

    k_prep    <<<272, 256, 0, stream>>>(Watt, Wout, Whi, Wlo, Wth, Wtl);
    k_splitx  <<<2048, 256, 0, stream>>>(x, xh, xl);
    k_pack    <<<2048, 256, 0, stream>>>(adj, abits);
    k_gemm1   <<<dim3(64,8), 256, 0, stream>>>(xh, xl, Whi, Wlo, aatt, hT, ssrc2, sdst2);
    k_attn1   <<<dim3(64,8), 512, 0, stream>>>(hT, ssrc2, sdst2, (const uchar_t*)abits, hch, hcl);
    k_gemm2   <<<64, 256, 0, stream>>>(hch, hcl, Wth, Wtl, aout, h2T, ss2, sd2);
    k_attn2   <<<dim3(64,8), 256, 0, stream>>>(h2T, ss2, sd2, (const uchar_t*)abits, pnum2T, pden2);
    k_reduce2 <<<128, 256, 0, stream>>>(pnum2T, pden2, out);
}